// Round 1
// baseline (621.588 us; speedup 1.0000x reference)
//
#include <hip/hip_runtime.h>

// SigmoidLoss: loss_ij = t_ij * log(clip(sigmoid(x_ij), eps, 1-eps));
// per row take max over positive labels, negate, weight, mean over rows.
// Monotonicity of log∘clip∘sigmoid => max commutes: find max x over positives,
// apply the transform once per row. Pure masked-max reduction => memory-bound.

#define NROWS 16384
#define NCOLS 5000
#define NVEC  (NCOLS / 4)   // 1250, exact
#define EPSF  1e-6f

__global__ __launch_bounds__(256) void row_loss_kernel(
    const float* __restrict__ inp,
    const int*   __restrict__ tgt,
    const float* __restrict__ w,
    float*       __restrict__ row_loss)
{
    const int row = blockIdx.x;
    const float4* __restrict__ x4 = (const float4*)(inp + (size_t)row * NCOLS);
    const int4*   __restrict__ t4 = (const int4*)(tgt + (size_t)row * NCOLS);

    const float NEG = -3.0e38f;
    float m = NEG;
    for (int i = threadIdx.x; i < NVEC; i += 256) {
        float4 x = x4[i];
        int4   t = t4[i];
        m = fmaxf(m, (t.x > 0) ? x.x : NEG);
        m = fmaxf(m, (t.y > 0) ? x.y : NEG);
        m = fmaxf(m, (t.z > 0) ? x.z : NEG);
        m = fmaxf(m, (t.w > 0) ? x.w : NEG);
    }

    // wave (64-lane) max reduction
    #pragma unroll
    for (int off = 32; off > 0; off >>= 1)
        m = fmaxf(m, __shfl_xor(m, off, 64));

    __shared__ float smax[4];
    const int lane = threadIdx.x & 63;
    const int wid  = threadIdx.x >> 6;
    if (lane == 0) smax[wid] = m;
    __syncthreads();

    if (threadIdx.x == 0) {
        m = fmaxf(fmaxf(smax[0], smax[1]), fmaxf(smax[2], smax[3]));
        float loss = 0.0f;
        if (m > -1.0e38f) {  // row has at least one positive
            // logp = log(clamp(sigmoid(m), eps, 1-eps)); loss = -logp * w
            float p = 1.0f / (1.0f + expf(-m));
            p = fminf(fmaxf(p, EPSF), 1.0f - EPSF);
            loss = -logf(p) * w[row];
        }
        row_loss[row] = loss;  // written for every row => no ws pre-zero needed
    }
}

__global__ __launch_bounds__(256) void reduce_mean_kernel(
    const float* __restrict__ row_loss,
    float*       __restrict__ out)
{
    float s = 0.0f;
    for (int i = threadIdx.x; i < NROWS; i += 256)
        s += row_loss[i];

    #pragma unroll
    for (int off = 32; off > 0; off >>= 1)
        s += __shfl_xor(s, off, 64);

    __shared__ float ssum[4];
    const int lane = threadIdx.x & 63;
    const int wid  = threadIdx.x >> 6;
    if (lane == 0) ssum[wid] = s;
    __syncthreads();

    if (threadIdx.x == 0) {
        float tot = ssum[0] + ssum[1] + ssum[2] + ssum[3];
        out[0] = tot / (float)NROWS;
    }
}

extern "C" void kernel_launch(void* const* d_in, const int* in_sizes, int n_in,
                              void* d_out, int out_size, void* d_ws, size_t ws_size,
                              hipStream_t stream) {
    const float* inp = (const float*)d_in[0];
    const int*   tgt = (const int*)d_in[1];
    const float* w   = (const float*)d_in[2];
    float* row_loss  = (float*)d_ws;          // 16384 floats = 64 KB scratch
    float* out       = (float*)d_out;

    row_loss_kernel<<<NROWS, 256, 0, stream>>>(inp, tgt, w, row_loss);
    reduce_mean_kernel<<<1, 256, 0, stream>>>(row_loss, out);
}

// Round 3
// 586.367 us; speedup vs baseline: 1.0601x; 1.0601x over previous
//
#include <hip/hip_runtime.h>

// SigmoidLoss: loss_ij = t_ij * log(clip(sigmoid(x_ij), eps, 1-eps));
// per row: max over positive labels, negate, weight; then mean over rows.
// log∘clip∘sigmoid is monotone => masked max over x commutes with the
// transform: find max x over positives, transform once per row.
// Pure streaming masked-max reduction => memory-bound (655 MB, one pass).
//
// R2: ext_vector_type typedefs (HIP_vector_type structs are invalid for
// __builtin_nontemporal_load); fully-unrolled up-front loads + nt hints.

#define NROWS 16384
#define NCOLS 5000
#define NVEC  (NCOLS / 4)   // 1250 = 4*256 + 226, exact float4 count per row
#define EPSF  1e-6f

typedef float fvec4 __attribute__((ext_vector_type(4)));
typedef int   ivec4 __attribute__((ext_vector_type(4)));

__global__ __launch_bounds__(256) void row_loss_kernel(
    const float* __restrict__ inp,
    const int*   __restrict__ tgt,
    const float* __restrict__ w,
    float*       __restrict__ row_loss)
{
    const int row = blockIdx.x;
    const fvec4* __restrict__ x4 = (const fvec4*)(inp + (size_t)row * NCOLS);
    const ivec4* __restrict__ t4 = (const ivec4*)(tgt + (size_t)row * NCOLS);
    const int tid = threadIdx.x;

    const float NEG = -3.0e38f;

    // Issue all 8 main loads up front: maximal memory-level parallelism.
    fvec4 x0 = __builtin_nontemporal_load(x4 + tid);
    fvec4 x1 = __builtin_nontemporal_load(x4 + tid + 256);
    fvec4 x2 = __builtin_nontemporal_load(x4 + tid + 512);
    fvec4 x3 = __builtin_nontemporal_load(x4 + tid + 768);
    ivec4 t0 = __builtin_nontemporal_load(t4 + tid);
    ivec4 t1 = __builtin_nontemporal_load(t4 + tid + 256);
    ivec4 t2 = __builtin_nontemporal_load(t4 + tid + 512);
    ivec4 t3 = __builtin_nontemporal_load(t4 + tid + 768);

    float m = NEG;
#define MASKED_MAX(x, t)                                    \
    do {                                                    \
        m = fmaxf(m, ((t)[0] > 0) ? (x)[0] : NEG);          \
        m = fmaxf(m, ((t)[1] > 0) ? (x)[1] : NEG);          \
        m = fmaxf(m, ((t)[2] > 0) ? (x)[2] : NEG);          \
        m = fmaxf(m, ((t)[3] > 0) ? (x)[3] : NEG);          \
    } while (0)

    MASKED_MAX(x0, t0);
    MASKED_MAX(x1, t1);
    MASKED_MAX(x2, t2);
    MASKED_MAX(x3, t3);

    // Tail: 1250 - 1024 = 226 vectors
    if (tid < (NVEC - 1024)) {
        fvec4 xt = __builtin_nontemporal_load(x4 + tid + 1024);
        ivec4 tt = __builtin_nontemporal_load(t4 + tid + 1024);
        MASKED_MAX(xt, tt);
    }
#undef MASKED_MAX

    // wave (64-lane) max reduction
    #pragma unroll
    for (int off = 32; off > 0; off >>= 1)
        m = fmaxf(m, __shfl_xor(m, off, 64));

    __shared__ float smax[4];
    const int lane = tid & 63;
    const int wid  = tid >> 6;
    if (lane == 0) smax[wid] = m;
    __syncthreads();

    if (tid == 0) {
        m = fmaxf(fmaxf(smax[0], smax[1]), fmaxf(smax[2], smax[3]));
        float loss = 0.0f;
        if (m > -1.0e38f) {  // row has at least one positive
            // logp = log(clamp(sigmoid(m), eps, 1-eps)); loss = -logp * w
            float p = 1.0f / (1.0f + __expf(-m));
            p = fminf(fmaxf(p, EPSF), 1.0f - EPSF);
            loss = -logf(p) * w[row];
        }
        row_loss[row] = loss;  // written for every row => no ws pre-zero needed
    }
}

__global__ __launch_bounds__(256) void reduce_mean_kernel(
    const float* __restrict__ row_loss,
    float*       __restrict__ out)
{
    float s = 0.0f;
    for (int i = threadIdx.x; i < NROWS; i += 256)
        s += row_loss[i];

    #pragma unroll
    for (int off = 32; off > 0; off >>= 1)
        s += __shfl_xor(s, off, 64);

    __shared__ float ssum[4];
    const int lane = threadIdx.x & 63;
    const int wid  = threadIdx.x >> 6;
    if (lane == 0) ssum[wid] = s;
    __syncthreads();

    if (threadIdx.x == 0) {
        float tot = ssum[0] + ssum[1] + ssum[2] + ssum[3];
        out[0] = tot / (float)NROWS;
    }
}

extern "C" void kernel_launch(void* const* d_in, const int* in_sizes, int n_in,
                              void* d_out, int out_size, void* d_ws, size_t ws_size,
                              hipStream_t stream) {
    const float* inp = (const float*)d_in[0];
    const int*   tgt = (const int*)d_in[1];
    const float* w   = (const float*)d_in[2];
    float* row_loss  = (float*)d_ws;          // 16384 floats = 64 KB scratch
    float* out       = (float*)d_out;

    row_loss_kernel<<<NROWS, 256, 0, stream>>>(inp, tgt, w, row_loss);
    reduce_mean_kernel<<<1, 256, 0, stream>>>(row_loss, out);
}

// Round 5
// 571.778 us; speedup vs baseline: 1.0871x; 1.0255x over previous
//
#include <hip/hip_runtime.h>

// SigmoidLoss: loss_ij = t_ij * log(clip(sigmoid(x_ij), eps, 1-eps));
// per row: max over positive labels, negate, weight; then mean over rows.
// log∘clip∘sigmoid is monotone => masked max over x commutes with the
// transform: find max x over positives, transform once per row.
// Pure streaming masked-max reduction => memory-bound (655 MB, one pass).
//
// R5: fix R4's reduce bug — 16384 floats = 4096 float4 but only 1024 threads,
// so each thread must read FOUR float4s (R4 read one => summed 1/4 of rows,
// output was exactly ref/4). Hot kernel unchanged: wave-per-row, no LDS /
// __syncthreads (no vmcnt(0) barrier drain), 10 nt-loads in flight per group.

#define NROWS 16384
#define NCOLS 5000
#define NVEC  (NCOLS / 4)   // 1250 = 19*64 + 34
#define EPSF  1e-6f

typedef float fvec4 __attribute__((ext_vector_type(4)));
typedef int   ivec4 __attribute__((ext_vector_type(4)));

__global__ __launch_bounds__(256) void row_loss_kernel(
    const float* __restrict__ inp,
    const int*   __restrict__ tgt,
    const float* __restrict__ w,
    float*       __restrict__ row_loss)
{
    const int lane = threadIdx.x & 63;
    const int wid  = threadIdx.x >> 6;
    const int wave_global = blockIdx.x * 4 + wid;   // [0, 8192)
    const float NEG = -3.0e38f;

    #pragma unroll
    for (int rr = 0; rr < 2; ++rr) {
        const int row = wave_global * 2 + rr;       // [0, 16384), exact cover
        const fvec4* __restrict__ x4 = (const fvec4*)(inp + (size_t)row * NCOLS);
        const ivec4* __restrict__ t4 = (const ivec4*)(tgt + (size_t)row * NCOLS);

        float m = NEG;
        #pragma unroll
        for (int g = 0; g < 4; ++g) {
            fvec4 xv[5];
            ivec4 tv[5];
            // issue 10 loads back-to-back (deep MLP), then consume
            #pragma unroll
            for (int k = 0; k < 5; ++k) {
                const int idx = (g * 5 + k) * 64 + lane;
                if (idx < NVEC) {   // only predicated for chunk 19, lane>=34
                    xv[k] = __builtin_nontemporal_load(x4 + idx);
                    tv[k] = __builtin_nontemporal_load(t4 + idx);
                } else {
                    xv[k] = (fvec4)0.0f;
                    tv[k] = (ivec4)0;
                }
            }
            #pragma unroll
            for (int k = 0; k < 5; ++k) {
                m = fmaxf(m, (tv[k][0] > 0) ? xv[k][0] : NEG);
                m = fmaxf(m, (tv[k][1] > 0) ? xv[k][1] : NEG);
                m = fmaxf(m, (tv[k][2] > 0) ? xv[k][2] : NEG);
                m = fmaxf(m, (tv[k][3] > 0) ? xv[k][3] : NEG);
            }
        }

        // wave (64-lane) max reduction — register-only, no LDS, no barrier
        #pragma unroll
        for (int off = 32; off > 0; off >>= 1)
            m = fmaxf(m, __shfl_xor(m, off, 64));

        if (lane == 0) {
            float loss = 0.0f;
            if (m > -1.0e38f) {  // row has at least one positive
                float p = 1.0f / (1.0f + __expf(-m));
                p = fminf(fmaxf(p, EPSF), 1.0f - EPSF);
                loss = -logf(p) * w[row];
            }
            row_loss[row] = loss;  // every row written => no ws pre-zero needed
        }
    }
}

__global__ __launch_bounds__(1024) void reduce_mean_kernel(
    const float* __restrict__ row_loss,
    float*       __restrict__ out)
{
    // 16384 floats = 4096 float4; 1024 threads x FOUR float4 each.
    const fvec4* __restrict__ rl4 = (const fvec4*)row_loss;
    float s = 0.0f;
    #pragma unroll
    for (int j = 0; j < 4; ++j) {
        fvec4 v = rl4[threadIdx.x + j * 1024];
        s += (v[0] + v[1]) + (v[2] + v[3]);
    }

    #pragma unroll
    for (int off = 32; off > 0; off >>= 1)
        s += __shfl_xor(s, off, 64);

    __shared__ float ssum[16];
    const int lane = threadIdx.x & 63;
    const int wid  = threadIdx.x >> 6;
    if (lane == 0) ssum[wid] = s;
    __syncthreads();

    if (threadIdx.x == 0) {
        float tot = 0.0f;
        #pragma unroll
        for (int i = 0; i < 16; ++i) tot += ssum[i];
        out[0] = tot / (float)NROWS;
    }
}

extern "C" void kernel_launch(void* const* d_in, const int* in_sizes, int n_in,
                              void* d_out, int out_size, void* d_ws, size_t ws_size,
                              hipStream_t stream) {
    const float* inp = (const float*)d_in[0];
    const int*   tgt = (const int*)d_in[1];
    const float* w   = (const float*)d_in[2];
    float* row_loss  = (float*)d_ws;          // 16384 floats = 64 KB scratch
    float* out       = (float*)d_out;

    row_loss_kernel<<<2048, 256, 0, stream>>>(inp, tgt, w, row_loss);
    reduce_mean_kernel<<<1, 1024, 0, stream>>>(row_loss, out);
}